// Round 4
// baseline (54.952 us; speedup 1.0000x reference)
//
#include <hip/hip_runtime.h>

#define NFFT 2048
#define TT   512
#define BB   4
#define OUTL 261632        // per-batch trimmed output length

__device__ __forceinline__ float2 cmul(float2 a, float2 w) {
    return make_float2(a.x * w.x - a.y * w.y, a.x * w.y + a.y * w.x);
}

// radix-4 DIT butterfly (inverse transform, +i), twiddles w1, w1^2, w1^3
__device__ __forceinline__ void bf4(const float2 a[4], float2 o[4], float2 w1) {
    float2 w2 = make_float2(w1.x * w1.x - w1.y * w1.y, 2.f * w1.x * w1.y);
    float2 w3 = cmul(w1, w2);
    float t0r = a[0].x + a[2].x, t0i = a[0].y + a[2].y;
    float t1r = a[0].x - a[2].x, t1i = a[0].y - a[2].y;
    float t2r = a[1].x + a[3].x, t2i = a[1].y + a[3].y;
    float t3r = a[3].y - a[1].y, t3i = a[1].x - a[3].x;   // i*(a1-a3)
    o[0] = make_float2(t0r + t2r, t0i + t2i);
    o[1] = cmul(make_float2(t1r + t3r, t1i + t3i), w1);
    o[2] = cmul(make_float2(t0r - t2r, t0i - t2i), w2);
    o[3] = cmul(make_float2(t1r - t3r, t1i - t3i), w3);
}

// LDS index swizzles (round-specific, bijective involutions)
template<int SIG> __device__ __forceinline__ int sig(int x) {
    if constexpr (SIG == 0) return x;
    else if constexpr (SIG == 2) return x ^ (((x >> 5) & 3) << 2);
    else                        return x ^ (((x >> 6) & 1) << 4);
}

template<int SBITS, int SR, int SW>
__device__ __forceinline__ void midstage(float* bR, float* bI, int tid2,
                                         const float* tw_c, const float* tw_s) {
    const int s = 1 << SBITS;
    float2 ra[4], rb[4];
#pragma unroll
    for (int q = 0; q < 4; q++) {
        int a1 = sig<SR>(tid2 + 512 * q);
        int a2 = sig<SR>(tid2 + 256 + 512 * q);
        ra[q] = make_float2(bR[a1], bI[a1]);
        rb[q] = make_float2(bR[a2], bI[a2]);
    }
    __syncthreads();
    const int mA = tid2 & ~(s - 1), rA = tid2 & (s - 1);
    const int mB = (tid2 + 256) & ~(s - 1), rB = (tid2 + 256) & (s - 1);
    float2 wA = make_float2(tw_c[mA], tw_s[mA]);
    float2 wB = make_float2(tw_c[mB], tw_s[mB]);
    float2 oA[4], oB[4];
    bf4(ra, oA, wA);
    bf4(rb, oB, wB);
    const int jA = 4 * mA + rA, jB = 4 * mB + rB;
#pragma unroll
    for (int k = 0; k < 4; k++) {
        int d1 = sig<SW>(jA + k * s);
        int d2 = sig<SW>(jB + k * s);
        bR[d1] = oA[k].x; bI[d1] = oA[k].y;
        bR[d2] = oB[k].x; bI[d2] = oB[k].y;
    }
    __syncthreads();
}

// Fused iSTFT: one block = one 2048-sample output region (4 strides).
// 512 threads = 2 x 256-thread FFT halves; 7 columns over 4 rounds; OLA in regs.
__global__ __launch_bounds__(512) void istft_k(const float* __restrict__ X,
                                               const float* __restrict__ kc,
                                               const float* __restrict__ ks,
                                               const float* __restrict__ win,
                                               float* __restrict__ out) {
    __shared__ float bR[2][2048];
    __shared__ float bI[2][2048];
    __shared__ float fr[2][2048];

    const int S = blockIdx.x;
    // XCD-aware remap: XCD x gets 64 contiguous regions (halo columns L2-shared)
    const int G = ((S & 7) << 6) + (S >> 3);
    const int b = G >> 7;              // batch
    const int R = G & 127;             // region within batch
    const int tidall = threadIdx.x;    // 0..511
    const int h = tidall >> 8;         // FFT half
    const int tid2 = tidall & 255;
    const float* tw_c = kc + 2048;     // cos(2*pi*m/2048) (kernel row n=1)
    const float* tw_s = ks + 2048;     // +sin (inverse transform)
    float* hbR = bR[h];
    float* hbI = bI[h];

    float acc[4] = {0.f, 0.f, 0.f, 0.f};

#pragma unroll 1
    for (int round = 0; round < 4; ++round) {
        const int m = 2 * round + h;           // column slot 0..7
        const int t = 4 * R - 1 + m;           // column time index
        const bool valid = (t >= 0) && (t < TT) && (m < 7);

        // ---- stage 1 (radix-4, s=1) fused with global load ----
        const float* Xb = X + (((size_t)b * 2048) * 512 + (valid ? t : 0)) * 2;
        float2 xa[4], xb_[4];
#pragma unroll
        for (int q = 0; q < 4; q++) {
            if (valid) {
                xa[q]  = *reinterpret_cast<const float2*>(Xb + (size_t)(tid2 + 512 * q) * 1024);
                xb_[q] = *reinterpret_cast<const float2*>(Xb + (size_t)(tid2 + 256 + 512 * q) * 1024);
            } else {
                xa[q] = make_float2(0.f, 0.f);
                xb_[q] = make_float2(0.f, 0.f);
            }
        }
        float2 w1a = make_float2(tw_c[tid2], tw_s[tid2]);
        float2 w1b = make_float2(tw_c[tid2 + 256], tw_s[tid2 + 256]);
        float2 oA[4], oB[4];
        bf4(xa, oA, w1a);
        bf4(xb_, oB, w1b);
        *reinterpret_cast<float4*>(hbR + 4 * tid2)         = make_float4(oA[0].x, oA[1].x, oA[2].x, oA[3].x);
        *reinterpret_cast<float4*>(hbI + 4 * tid2)         = make_float4(oA[0].y, oA[1].y, oA[2].y, oA[3].y);
        *reinterpret_cast<float4*>(hbR + 4 * (tid2 + 256)) = make_float4(oB[0].x, oB[1].x, oB[2].x, oB[3].x);
        *reinterpret_cast<float4*>(hbI + 4 * (tid2 + 256)) = make_float4(oB[0].y, oB[1].y, oB[2].y, oB[3].y);
        __syncthreads();

        // ---- mid stages s=4, 16, 64 ----
        midstage<2, 0, 2>(hbR, hbI, tid2, tw_c, tw_s);
        midstage<4, 2, 3>(hbR, hbI, tid2, tw_c, tw_s);
        midstage<6, 3, 0>(hbR, hbI, tid2, tw_c, tw_s);

        // ---- fused final: radix-4 (s=256) + radix-2 (s=1024), real parts only ----
        float2 aA[4], aB[4];
#pragma unroll
        for (int q = 0; q < 4; q++) {
            aA[q] = make_float2(hbR[tid2 + 512 * q],       hbI[tid2 + 512 * q]);
            aB[q] = make_float2(hbR[tid2 + 256 + 512 * q], hbI[tid2 + 256 + 512 * q]);
        }
        float At0r = aA[0].x + aA[2].x;
        float At1r = aA[0].x - aA[2].x;
        float At2r = aA[1].x + aA[3].x;
        float At3r = aA[3].y - aA[1].y;
        float PA0 = At0r + At2r;
        float PA1 = At1r + At3r;
        float PA2 = At0r - At2r;
        float PA3 = At1r - At3r;
        float Bt0r = aB[0].x + aB[2].x, Bt0i = aB[0].y + aB[2].y;
        float Bt1r = aB[0].x - aB[2].x, Bt1i = aB[0].y - aB[2].y;
        float Bt2r = aB[1].x + aB[3].x, Bt2i = aB[1].y + aB[3].y;
        float Bt3r = aB[3].y - aB[1].y, Bt3i = aB[1].x - aB[3].x;
        const float hc = 0.70710678118654752f;
        float PB0 = Bt0r + Bt2r;
        float u1r = Bt1r + Bt3r, u1i = Bt1i + Bt3i;
        float PB1 = hc * (u1r - u1i);
        float PB2 = -(Bt0i - Bt2i);
        float u3r = Bt1r - Bt3r, u3i = Bt1i - Bt3i;
        float PB3 = -hc * (u3r + u3i);

        // windowed frame -> LDS
        float* fh = fr[h];
        fh[tid2]        = (PA0 + PB0) * win[tid2];
        fh[tid2 + 256]  = (PA1 + PB1) * win[tid2 + 256];
        fh[tid2 + 512]  = (PA2 + PB2) * win[tid2 + 512];
        fh[tid2 + 768]  = (PA3 + PB3) * win[tid2 + 768];
        fh[tid2 + 1024] = (PA0 - PB0) * win[tid2 + 1024];
        fh[tid2 + 1280] = (PA1 - PB1) * win[tid2 + 1280];
        fh[tid2 + 1536] = (PA2 - PB2) * win[tid2 + 1536];
        fh[tid2 + 1792] = (PA3 - PB3) * win[tid2 + 1792];
        __syncthreads();

        // ---- overlap-add both halves into register accumulators ----
#pragma unroll
        for (int hh = 0; hh < 2; hh++) {
            int mm = 2 * round + hh;
            int base = tidall + 1536 - (mm << 9);   // n for q=0
#pragma unroll
            for (int q = 0; q < 4; q++) {
                int n = base + (q << 9);
                if (n >= 0 && n < 2048) acc[q] += fr[hh][n];
            }
        }
        __syncthreads();
    }

    // ---- normalize by window sum-square, trim, write ----
#pragma unroll
    for (int q = 0; q < 4; q++) {
        int jl = tidall + (q << 9);
        int jp = (R << 11) + jl;          // trimmed output index
        if (jp < OUTL) {
            int j = jp + 1024;            // untrimmed sample index
            int tb = j >> 9, r = j & 511;
            float ws = 0.f;
#pragma unroll
            for (int k = 0; k < 4; k++) {
                int t = tb - k;
                if (t >= 0 && t < TT) {
                    float w = win[r + (k << 9)];
                    ws += w * w;
                }
            }
            float y = acc[q] * (1.0f / 2048.0f);
            if (ws > 1e-10f) y /= ws;
            out[(size_t)b * OUTL + jp] = y;
        }
    }
}

extern "C" void kernel_launch(void* const* d_in, const int* in_sizes, int n_in,
                              void* d_out, int out_size, void* d_ws, size_t ws_size,
                              hipStream_t stream) {
    const float* X  = (const float*)d_in[0];
    const float* kc = (const float*)d_in[1];
    const float* ks = (const float*)d_in[2];
    const float* w  = (const float*)d_in[3];
    float* out = (float*)d_out;

    istft_k<<<dim3(BB * 128), dim3(512), 0, stream>>>(X, kc, ks, w, out);
}

// Round 5
// 34.494 us; speedup vs baseline: 1.5931x; 1.5931x over previous
//
#include <hip/hip_runtime.h>

#define NFFT 2048
#define TT   512
#define BB   4
#define OUTL 261632        // per-batch trimmed output length
#define OUTTOT (BB*OUTL)

// per-phase LDS swizzles (involutions, keep b64 accesses at bank floor)
__device__ __forceinline__ int sigA(int c) { return c ^ ((c >> 4) & 7); }
__device__ __forceinline__ int sig2(int c) { return c ^ (((c >> 6) & 1) << 3); }

__device__ __forceinline__ float2 cmul(float2 a, float2 w) {
    return make_float2(a.x * w.x - a.y * w.y, a.x * w.y + a.y * w.x);
}

// inverse 8-point DFT (+i convention): o[k] = sum_l a[l] e^{+2pi i k l/8}
__device__ __forceinline__ void dft8(const float2 a[8], float2 o[8]) {
    float e0r = a[0].x + a[4].x, e0i = a[0].y + a[4].y;
    float e1r = a[0].x - a[4].x, e1i = a[0].y - a[4].y;
    float e2r = a[2].x + a[6].x, e2i = a[2].y + a[6].y;
    float e3r = a[6].y - a[2].y, e3i = a[2].x - a[6].x;   // i*(a2-a6)
    float E0r = e0r + e2r, E0i = e0i + e2i;
    float E1r = e1r + e3r, E1i = e1i + e3i;
    float E2r = e0r - e2r, E2i = e0i - e2i;
    float E3r = e1r - e3r, E3i = e1i - e3i;
    float f0r = a[1].x + a[5].x, f0i = a[1].y + a[5].y;
    float f1r = a[1].x - a[5].x, f1i = a[1].y - a[5].y;
    float f2r = a[3].x + a[7].x, f2i = a[3].y + a[7].y;
    float f3r = a[7].y - a[3].y, f3i = a[3].x - a[7].x;   // i*(a3-a7)
    float O0r = f0r + f2r, O0i = f0i + f2i;
    float O1r = f1r + f3r, O1i = f1i + f3i;
    float O2r = f0r - f2r, O2i = f0i - f2i;
    float O3r = f1r - f3r, O3i = f1i - f3i;
    const float h = 0.70710678118654752f;
    float W1r = h * (O1r - O1i), W1i = h * (O1r + O1i);   // w^1 * O1
    float W2r = -O2i,            W2i = O2r;               // i * O2
    float W3r = -h * (O3r + O3i), W3i = h * (O3r - O3i);  // w^3 * O3
    o[0] = make_float2(E0r + O0r, E0i + O0i);
    o[1] = make_float2(E1r + W1r, E1i + W1i);
    o[2] = make_float2(E2r + W2r, E2i + W2i);
    o[3] = make_float2(E3r + W3r, E3i + W3i);
    o[4] = make_float2(E0r - O0r, E0i - O0i);
    o[5] = make_float2(E1r - W1r, E1i - W1i);
    o[6] = make_float2(E2r - W2r, E2i - W2i);
    o[7] = make_float2(E3r - W3r, E3i - W3i);
}

// o[k] *= w1^k (powers via in-register cmul chain)
__device__ __forceinline__ void twpow8(float2 o[8], float2 w1) {
    float2 w2 = cmul(w1, w1);
    float2 w3 = cmul(w2, w1);
    float2 w4 = cmul(w2, w2);
    o[1] = cmul(o[1], w1);
    o[2] = cmul(o[2], w2);
    o[3] = cmul(o[3], w3);
    o[4] = cmul(o[4], w4);
    o[5] = cmul(o[5], cmul(w4, w1));
    o[6] = cmul(o[6], cmul(w4, w2));
    o[7] = cmul(o[7], cmul(w4, w3));
}

// One block per (b,t) column: 2048-pt inverse DFT = radix 8*8*8*4, real parts out.
__global__ __launch_bounds__(256) void fft_k(const float* __restrict__ X,
                                             const float* __restrict__ kc,
                                             const float* __restrict__ ks,
                                             float* __restrict__ Ft) {
    __shared__ float2 buf[2048];
    __shared__ float2 twL[32];          // tw[8m], m<32  (covers stages B and C)
    const int S = blockIdx.x;
    // XCD-aware remap: XCD x owns contiguous columns (t-adjacent blocks share X lines)
    const int c = ((S & 7) << 8) + (((S >> 6) & 31) << 3) + ((S >> 3) & 7);
    const int b = c >> 9;
    const int t = c & 511;
    const int u = threadIdx.x;          // 0..255
    const float* tw_c = kc + 2048;      // cos(2*pi*m/2048) (kernel row n=1)
    const float* tw_s = ks + 2048;      // +sin (inverse transform)

    if (u < 32) twL[u] = make_float2(tw_c[u << 3], tw_s[u << 3]);

    // ---- stage A: radix-8, s=1, fused with global load ----
    const float* Xb = X + ((size_t)b * 2048 * 512 + t) * 2;
    float2 a[8], o[8];
    #pragma unroll
    for (int l = 0; l < 8; l++)
        a[l] = *reinterpret_cast<const float2*>(Xb + (size_t)(u + 256 * l) * 1024);
    dft8(a, o);
    twpow8(o, make_float2(tw_c[u], tw_s[u]));
    #pragma unroll
    for (int k = 0; k < 8; k++) buf[sigA(8 * u + k)] = o[k];
    __syncthreads();

    // ---- stage B: radix-8, s=8 ----
    #pragma unroll
    for (int l = 0; l < 8; l++) a[l] = buf[sigA(u + 256 * l)];
    __syncthreads();
    dft8(a, o);
    twpow8(o, twL[u >> 3]);             // tw[u & ~7]
    {
        int base = 64 * (u >> 3) + (u & 7);
        #pragma unroll
        for (int k = 0; k < 8; k++) buf[sig2(base + 8 * k)] = o[k];
    }
    __syncthreads();

    // ---- stage C: radix-8, s=64 ----
    #pragma unroll
    for (int l = 0; l < 8; l++) a[l] = buf[sig2(u + 256 * l)];
    __syncthreads();
    dft8(a, o);
    twpow8(o, twL[(u >> 6) << 3]);      // tw[u & ~63]
    {
        int base = 512 * (u >> 6) + (u & 63);
        #pragma unroll
        for (int k = 0; k < 8; k++) buf[base + 64 * k] = o[k];
    }
    __syncthreads();

    // ---- stage D: radix-4, s=512, w=1: real parts only, fused store ----
    float* outp = Ft + (size_t)c * 2048;
    #pragma unroll
    for (int half = 0; half < 2; half++) {
        int uu = u + 256 * half;
        float2 d0 = buf[uu], d1 = buf[uu + 512], d2 = buf[uu + 1024], d3 = buf[uu + 1536];
        float t0 = d0.x + d2.x;
        float t1 = d0.x - d2.x;
        float t2 = d1.x + d3.x;
        float t3 = d3.y - d1.y;          // Re(i*(d1-d3))
        outp[uu]        = t0 + t2;
        outp[uu + 512]  = t1 + t3;
        outp[uu + 1024] = t0 - t2;
        outp[uu + 1536] = t1 - t3;
    }
}

// ---- OLA + window sumsquare normalization + trim ----
__global__ __launch_bounds__(256) void ola_k(const float* __restrict__ Ft,
                                             const float* __restrict__ win,
                                             float* __restrict__ out) {
    int j1 = blockIdx.x * 256 + threadIdx.x;
    if (j1 >= OUTTOT) return;
    int b  = j1 / OUTL;
    int jp = j1 - b * OUTL;
    int j  = jp + 1024;             // untrimmed sample index
    int tbase = j >> 9;
    int r = j & 511;
    float acc = 0.f, ws = 0.f;
    #pragma unroll
    for (int k = 0; k < 4; k++) {
        int t = tbase - k;
        if (t >= 0 && t < TT) {
            int n = r + (k << 9);
            float w = win[n];
            acc += Ft[(size_t)(b * TT + t) * NFFT + n] * w;
            ws  += w * w;
        }
    }
    float y = acc * (1.0f / (float)NFFT);
    if (ws > 1e-10f) y /= ws;
    out[j1] = y;
}

extern "C" void kernel_launch(void* const* d_in, const int* in_sizes, int n_in,
                              void* d_out, int out_size, void* d_ws, size_t ws_size,
                              hipStream_t stream) {
    const float* X  = (const float*)d_in[0];
    const float* kc = (const float*)d_in[1];
    const float* ks = (const float*)d_in[2];
    const float* w  = (const float*)d_in[3];
    float* out = (float*)d_out;

    float* Ft = (float*)d_ws;                     // 2048*2048 f32 = 16.8 MB

    fft_k<<<dim3(BB * TT), dim3(256), 0, stream>>>(X, kc, ks, Ft);
    ola_k<<<dim3((OUTTOT + 255) / 256), dim3(256), 0, stream>>>(Ft, w, out);
}

// Round 6
// 31.627 us; speedup vs baseline: 1.7375x; 1.0906x over previous
//
#include <hip/hip_runtime.h>

#define NFFT 2048
#define TT   512
#define BB   4
#define OUTL 261632        // per-batch trimmed output length
#define OUTTOT (BB*OUTL)

// tile storage: T(i,c) at float2 index i*8 + slot(i,c); rotation spreads banks
__device__ __forceinline__ int TIDX(int i, int c) {
    return i * 8 + ((c + i + (i >> 3)) & 7);
}

__device__ __forceinline__ float2 cmul(float2 a, float2 w) {
    return make_float2(a.x * w.x - a.y * w.y, a.x * w.y + a.y * w.x);
}

// inverse 8-point DFT (+i convention): o[k] = sum_l a[l] e^{+2pi i k l/8}
__device__ __forceinline__ void dft8(const float2 a[8], float2 o[8]) {
    float e0r = a[0].x + a[4].x, e0i = a[0].y + a[4].y;
    float e1r = a[0].x - a[4].x, e1i = a[0].y - a[4].y;
    float e2r = a[2].x + a[6].x, e2i = a[2].y + a[6].y;
    float e3r = a[6].y - a[2].y, e3i = a[2].x - a[6].x;   // i*(a2-a6)
    float E0r = e0r + e2r, E0i = e0i + e2i;
    float E1r = e1r + e3r, E1i = e1i + e3i;
    float E2r = e0r - e2r, E2i = e0i - e2i;
    float E3r = e1r - e3r, E3i = e1i - e3i;
    float f0r = a[1].x + a[5].x, f0i = a[1].y + a[5].y;
    float f1r = a[1].x - a[5].x, f1i = a[1].y - a[5].y;
    float f2r = a[3].x + a[7].x, f2i = a[3].y + a[7].y;
    float f3r = a[7].y - a[3].y, f3i = a[3].x - a[7].x;   // i*(a3-a7)
    float O0r = f0r + f2r, O0i = f0i + f2i;
    float O1r = f1r + f3r, O1i = f1i + f3i;
    float O2r = f0r - f2r, O2i = f0i - f2i;
    float O3r = f1r - f3r, O3i = f1i - f3i;
    const float h = 0.70710678118654752f;
    float W1r = h * (O1r - O1i), W1i = h * (O1r + O1i);   // w^1 * O1
    float W2r = -O2i,            W2i = O2r;               // i * O2
    float W3r = -h * (O3r + O3i), W3i = h * (O3r - O3i);  // w^3 * O3
    o[0] = make_float2(E0r + O0r, E0i + O0i);
    o[1] = make_float2(E1r + W1r, E1i + W1i);
    o[2] = make_float2(E2r + W2r, E2i + W2i);
    o[3] = make_float2(E3r + W3r, E3i + W3i);
    o[4] = make_float2(E0r - O0r, E0i - O0i);
    o[5] = make_float2(E1r - W1r, E1i - W1i);
    o[6] = make_float2(E2r - W2r, E2i - W2i);
    o[7] = make_float2(E3r - W3r, E3i - W3i);
}

// o[k] *= w1^k (powers via in-register cmul chain)
__device__ __forceinline__ void twpow8(float2 o[8], float2 w1) {
    float2 w2 = cmul(w1, w1);
    float2 w3 = cmul(w2, w1);
    float2 w4 = cmul(w2, w2);
    o[1] = cmul(o[1], w1);
    o[2] = cmul(o[2], w2);
    o[3] = cmul(o[3], w3);
    o[4] = cmul(o[4], w4);
    o[5] = cmul(o[5], cmul(w4, w1));
    o[6] = cmul(o[6], cmul(w4, w2));
    o[7] = cmul(o[7], cmul(w4, w3));
}

// One block = 8 consecutive t-columns. 1024 threads stage the 128KB tile with
// full-line coalesced loads (each HBM line read exactly once chip-wide), then
// 4 x 256-thread groups run the radix-8*8*8*4 inverse FFT in place (2 rounds).
__global__ __launch_bounds__(1024) void fft_k(const float* __restrict__ X,
                                              const float* __restrict__ kc,
                                              const float* __restrict__ ks,
                                              float* __restrict__ Ft) {
    __shared__ float2 tile[2048 * 8];      // 128 KiB
    __shared__ float2 tw256[256];          // e^{+2pi i m/2048}, m<256

    const int S  = blockIdx.x;
    const int c0 = S * 8;                  // global column base (c = b*512+t)
    const int b  = c0 >> 9;
    const int t0 = c0 & 511;               // multiple of 8
    const int tid = threadIdx.x;           // 0..1023

    if (tid < 256)
        tw256[tid] = make_float2(kc[2048 + tid], ks[2048 + tid]);

    // ---- phase 0: stage tile, full 64B lines per wave-instruction ----
    const float* Xb = X + ((size_t)b * 2048 * 512 + t0) * 2;
    #pragma unroll
    for (int m = 0; m < 8; m++) {
        int f = m * 256 + (tid >> 2);
        int c = (tid & 3) * 2;
        const float4 v = *reinterpret_cast<const float4*>(Xb + ((size_t)f * 512 + c) * 2);
        tile[TIDX(f, c)]     = make_float2(v.x, v.y);
        tile[TIDX(f, c + 1)] = make_float2(v.z, v.w);
    }
    __syncthreads();

    // ---- 2 rounds x 4 columns; group g = tid>>8 owns column c = 4r+g ----
    const int g = tid >> 8;
    const int u = tid & 255;
    #pragma unroll 1
    for (int r = 0; r < 2; r++) {
        const int c = r * 4 + g;
        float2 a[8], o[8];
        // stage A: radix-8, s=1
        #pragma unroll
        for (int l = 0; l < 8; l++) a[l] = tile[TIDX(u + 256 * l, c)];
        __syncthreads();
        dft8(a, o);
        twpow8(o, tw256[u]);
        #pragma unroll
        for (int k = 0; k < 8; k++) tile[TIDX(8 * u + k, c)] = o[k];
        __syncthreads();
        // stage B: radix-8, s=8
        #pragma unroll
        for (int l = 0; l < 8; l++) a[l] = tile[TIDX(u + 256 * l, c)];
        __syncthreads();
        dft8(a, o);
        twpow8(o, tw256[u & ~7]);
        {
            int base = 64 * (u >> 3) + (u & 7);
            #pragma unroll
            for (int k = 0; k < 8; k++) tile[TIDX(base + 8 * k, c)] = o[k];
        }
        __syncthreads();
        // stage C: radix-8, s=64
        #pragma unroll
        for (int l = 0; l < 8; l++) a[l] = tile[TIDX(u + 256 * l, c)];
        __syncthreads();
        dft8(a, o);
        twpow8(o, tw256[u & ~63]);
        {
            int base = 512 * (u >> 6) + (u & 63);
            #pragma unroll
            for (int k = 0; k < 8; k++) tile[TIDX(base + 64 * k, c)] = o[k];
        }
        __syncthreads();
        // stage D: radix-4, s=512, w=1: real parts only, fused store
        float* outp = Ft + (size_t)(c0 + c) * 2048;
        #pragma unroll
        for (int half = 0; half < 2; half++) {
            int uu = u + 256 * half;
            float2 d0 = tile[TIDX(uu, c)];
            float2 d1 = tile[TIDX(uu + 512, c)];
            float2 d2 = tile[TIDX(uu + 1024, c)];
            float2 d3 = tile[TIDX(uu + 1536, c)];
            float p0 = d0.x + d2.x;
            float p1 = d0.x - d2.x;
            float p2 = d1.x + d3.x;
            float p3 = d3.y - d1.y;          // Re(i*(d1-d3))
            outp[uu]        = p0 + p2;
            outp[uu + 512]  = p1 + p3;
            outp[uu + 1024] = p0 - p2;
            outp[uu + 1536] = p1 - p3;
        }
        // no barrier needed between rounds: round r+1 touches disjoint columns,
        // and its A-read->A-write barrier orders it against round r's D-reads.
    }
}

// ---- OLA + window sumsquare normalization + trim ----
__global__ __launch_bounds__(256) void ola_k(const float* __restrict__ Ft,
                                             const float* __restrict__ win,
                                             float* __restrict__ out) {
    int j1 = blockIdx.x * 256 + threadIdx.x;
    if (j1 >= OUTTOT) return;
    int b  = j1 / OUTL;
    int jp = j1 - b * OUTL;
    int j  = jp + 1024;             // untrimmed sample index
    int tbase = j >> 9;
    int r = j & 511;
    float acc = 0.f, ws = 0.f;
    #pragma unroll
    for (int k = 0; k < 4; k++) {
        int t = tbase - k;
        if (t >= 0 && t < TT) {
            int n = r + (k << 9);
            float w = win[n];
            acc += Ft[(size_t)(b * TT + t) * NFFT + n] * w;
            ws  += w * w;
        }
    }
    float y = acc * (1.0f / (float)NFFT);
    if (ws > 1e-10f) y /= ws;
    out[j1] = y;
}

extern "C" void kernel_launch(void* const* d_in, const int* in_sizes, int n_in,
                              void* d_out, int out_size, void* d_ws, size_t ws_size,
                              hipStream_t stream) {
    const float* X  = (const float*)d_in[0];
    const float* kc = (const float*)d_in[1];
    const float* ks = (const float*)d_in[2];
    const float* w  = (const float*)d_in[3];
    float* out = (float*)d_out;

    float* Ft = (float*)d_ws;                     // 2048*2048 f32 = 16.8 MB

    fft_k<<<dim3(BB * TT / 8), dim3(1024), 0, stream>>>(X, kc, ks, Ft);
    ola_k<<<dim3((OUTTOT + 255) / 256), dim3(256), 0, stream>>>(Ft, w, out);
}